// Round 1
// baseline (49.968 us; speedup 1.0000x reference)
//
#include <hip/hip_runtime.h>
#include <hip/hip_bf16.h>

#define N_      2048
#define TWO_N   4096
#define DFEAT   128
#define SCALE   2.0f   // 1 / TEMPERATURE
#define CCHUNKS 8      // column chunks in k_simsum
#define CCOLS   (TWO_N / CCHUNKS)

typedef __attribute__((ext_vector_type(8))) short bf16x8;
typedef __attribute__((ext_vector_type(4))) float f32x4;

// ---------------------------------------------------------------------------
// Kernel 1: normalize rows of [anchor; pos] -> bf16 zn16[4096][128]
// ---------------------------------------------------------------------------
__global__ __launch_bounds__(64) void k_norm(const float* __restrict__ a,
                                             const float* __restrict__ p,
                                             __hip_bfloat16* __restrict__ zn16) {
  const int row  = blockIdx.x;     // 0..4095
  const int lane = threadIdx.x;    // 0..63, two floats each
  const float* src = (row < N_) ? (a + (size_t)row * DFEAT)
                                : (p + (size_t)(row - N_) * DFEAT);
  float2 v = ((const float2*)src)[lane];
  float ss = v.x * v.x + v.y * v.y;
#pragma unroll
  for (int m = 1; m < 64; m <<= 1) ss += __shfl_xor(ss, m);
  float rn = 1.0f / fmaxf(sqrtf(ss), 1e-8f);
  __hip_bfloat162 h;
  h.x = __float2bfloat16(v.x * rn);
  h.y = __float2bfloat16(v.y * rn);
  ((__hip_bfloat162*)zn16)[row * (DFEAT / 2) + lane] = h;
}

// ---------------------------------------------------------------------------
// Kernel 2: d[i] = 2 * cos_sim(anchor[i], neg[i])  (f32, straight from inputs)
// ---------------------------------------------------------------------------
__global__ __launch_bounds__(64) void k_dvec(const float* __restrict__ a,
                                             const float* __restrict__ ng,
                                             float* __restrict__ dvec) {
  const int i = blockIdx.x, lane = threadIdx.x;
  float2 u = ((const float2*)(a  + (size_t)i * DFEAT))[lane];
  float2 w = ((const float2*)(ng + (size_t)i * DFEAT))[lane];
  float san = u.x * w.x + u.y * w.y;
  float saa = u.x * u.x + u.y * u.y;
  float snn = w.x * w.x + w.y * w.y;
#pragma unroll
  for (int m = 1; m < 64; m <<= 1) {
    san += __shfl_xor(san, m);
    saa += __shfl_xor(saa, m);
    snn += __shfl_xor(snn, m);
  }
  if (lane == 0) {
    float rn = 1.0f / (fmaxf(sqrtf(saa), 1e-8f) * fmaxf(sqrtf(snn), 1e-8f));
    dvec[i] = SCALE * san * rn;
  }
}

// ---------------------------------------------------------------------------
// Kernel 3: fused G = zn@zn^T /T, exp, masked row-segment sums.
//   grid = (TWO_N/64 row strips, CCHUNKS col chunks), block = 256 (4 waves).
//   Each wave owns a 16-row strip; MFMA 16x16x32 bf16 over K=128.
//   C/D layout: col = lane&15, row = (lane>>4)*4 + reg   [m89-verified]
//   A: lane holds row (lane&15), k = (lane>>4)*8 + j (per 32-k subtile)
//   B: lane holds col (lane&15), same k layout  (B = zn^T so same addressing)
// ---------------------------------------------------------------------------
__global__ __launch_bounds__(256) void k_simsum(const __hip_bfloat16* __restrict__ zn16,
                                                float* __restrict__ accP,
                                                float* __restrict__ accS) {
  const int wave = threadIdx.x >> 6;
  const int lane = threadIdx.x & 63;
  const int lr   = lane & 15;   // A-row / B-col within tile
  const int kg   = lane >> 4;   // k-group
  const int rows_base = blockIdx.x * 64 + wave * 16;
  const int cb0 = blockIdx.y * CCOLS;
  const short* zs = (const short*)zn16;

  // A fragments for this wave's 16 rows, all K=128 (4 subtiles), kept in regs
  bf16x8 a[4];
#pragma unroll
  for (int kk = 0; kk < 4; ++kk)
    a[kk] = *(const bf16x8*)(zs + (size_t)(rows_base + lr) * DFEAT + kk * 32 + kg * 8);

  const bool hi = (rows_base >= N_);   // strip-uniform (N_ % 16 == 0)
  int rrow[4], prt[4];
#pragma unroll
  for (int j = 0; j < 4; ++j) {
    rrow[j] = rows_base + kg * 4 + j;
    prt[j]  = hi ? (rrow[j] - N_) : (rrow[j] + N_);
  }

  float accPv[4] = {0.f, 0.f, 0.f, 0.f};
  float accSv[4] = {0.f, 0.f, 0.f, 0.f};

  for (int ct = 0; ct < CCOLS / 16; ++ct) {
    const int cb = cb0 + ct * 16;
    const int c  = cb + lr;
    bf16x8 b[4];
#pragma unroll
    for (int kk = 0; kk < 4; ++kk)
      b[kk] = *(const bf16x8*)(zs + (size_t)c * DFEAT + kk * 32 + kg * 8);
    f32x4 acc = {0.f, 0.f, 0.f, 0.f};
#pragma unroll
    for (int kk = 0; kk < 4; ++kk)
      acc = __builtin_amdgcn_mfma_f32_16x16x32_bf16(a[kk], b[kk], acc, 0, 0, 0);
#pragma unroll
    for (int j = 0; j < 4; ++j) {
      const int r = rrow[j];
      float e = __expf(SCALE * acc[j]);
      const bool excl = (c == r) || (c == prt[j]);  // diag + masked partner/q
      e = excl ? 0.0f : e;
      if (hi) {
        const bool toP = (c < prt[j]);              // prt = q = r - N
        accPv[j] += toP ? e : 0.0f;
        accSv[j] += toP ? 0.0f : e;
      } else {
        accSv[j] += e;
      }
    }
  }

  // reduce across the 16 lanes sharing this row group, then atomics
#pragma unroll
  for (int j = 0; j < 4; ++j) {
    float pv = accPv[j], sv = accSv[j];
#pragma unroll
    for (int m = 1; m < 16; m <<= 1) {
      pv += __shfl_xor(pv, m);
      sv += __shfl_xor(sv, m);
    }
    if (lr == 0) {
      atomicAdd(&accS[rrow[j]], sv);
      if (hi) atomicAdd(&accP[rrow[j]], pv);
    }
  }
}

// ---------------------------------------------------------------------------
// Kernel 4: finalize.
//   row i<N:       log(2*E[i] + accS[i]) - d[i]
//   row N+i, i<N-1: log(E[i] + accS[N+i] + accP[N+i+1]) - d[i]
//   row 2N-1:      log(E[N-1] + accS[2N-1] + sum_j E[j]) - d[N-1]
// ---------------------------------------------------------------------------
__global__ __launch_bounds__(1024) void k_final(const float* __restrict__ dvec,
                                                const float* __restrict__ accP,
                                                const float* __restrict__ accS,
                                                float* __restrict__ out) {
  __shared__ float Elds[N_];
  __shared__ float red[16];
  const int tid = threadIdx.x;
  float dpart = 0.f;
  for (int i = tid; i < N_; i += 1024) {
    float E = __expf(dvec[i]);
    Elds[i] = E;
    dpart += E;
  }
#pragma unroll
  for (int m = 1; m < 64; m <<= 1) dpart += __shfl_xor(dpart, m);
  const int w = tid >> 6, l = tid & 63;
  if (l == 0) red[w] = dpart;
  __syncthreads();
  float Dsum = 0.f;
#pragma unroll
  for (int k = 0; k < 16; ++k) Dsum += red[k];
  __syncthreads();  // before reusing red[]

  float part = 0.f;
  for (int r = tid; r < TWO_N; r += 1024) {
    float t;
    if (r < N_) {
      t = logf(2.0f * Elds[r] + accS[r]) - dvec[r];
    } else {
      const int i = r - N_;
      const float extra = (i < N_ - 1) ? accP[r + 1] : Dsum;
      t = logf(Elds[i] + accS[r] + extra) - dvec[i];
    }
    part += t;
  }
#pragma unroll
  for (int m = 1; m < 64; m <<= 1) part += __shfl_xor(part, m);
  if (l == 0) red[w] = part;
  __syncthreads();
  if (tid == 0) {
    float tot = 0.f;
#pragma unroll
    for (int k = 0; k < 16; ++k) tot += red[k];
    out[0] = tot / (float)TWO_N;
  }
}

// ---------------------------------------------------------------------------
extern "C" void kernel_launch(void* const* d_in, const int* in_sizes, int n_in,
                              void* d_out, int out_size, void* d_ws, size_t ws_size,
                              hipStream_t stream) {
  const float* a  = (const float*)d_in[0];
  const float* p  = (const float*)d_in[1];
  const float* ng = (const float*)d_in[2];

  char* ws = (char*)d_ws;
  __hip_bfloat16* zn16 = (__hip_bfloat16*)ws;                       // 1 MB
  float* dvec = (float*)(ws + (size_t)TWO_N * DFEAT * 2);           // 8 KB
  float* accP = (float*)(ws + (size_t)TWO_N * DFEAT * 2 + N_ * 4);  // 16 KB
  float* accS = accP + TWO_N;                                       // 16 KB

  // zero the atomic accumulators (accP + accS contiguous)
  hipMemsetAsync(accP, 0, 2 * TWO_N * sizeof(float), stream);

  k_norm<<<TWO_N, 64, 0, stream>>>(a, p, zn16);
  k_dvec<<<N_, 64, 0, stream>>>(a, ng, dvec);
  k_simsum<<<dim3(TWO_N / 64, CCHUNKS), 256, 0, stream>>>(zn16, accP, accS);
  k_final<<<1, 1024, 0, stream>>>(dvec, accP, accS, (float*)d_out);
}

// Round 2
// 46.135 us; speedup vs baseline: 1.0831x; 1.0831x over previous
//
#include <hip/hip_runtime.h>
#include <hip/hip_bf16.h>

#define N_      2048
#define TWO_N   4096
#define DFEAT   128
#define SCALE   2.0f   // 1 / TEMPERATURE
#define CCHUNKS 8      // column chunks in k_simsum
#define CCOLS   (TWO_N / CCHUNKS)

typedef __attribute__((ext_vector_type(8))) short bf16x8;
typedef __attribute__((ext_vector_type(4))) float f32x4;

// ---------------------------------------------------------------------------
// Kernel 1 (fused prep):
//   row < N : normalize anchor row -> zn16[row], AND dvec[row] = 2*cos(a,neg)
//   row >= N: normalize pos row   -> zn16[row]
// ---------------------------------------------------------------------------
__global__ __launch_bounds__(64) void k_prep(const float* __restrict__ a,
                                             const float* __restrict__ p,
                                             const float* __restrict__ ng,
                                             __hip_bfloat16* __restrict__ zn16,
                                             float* __restrict__ dvec) {
  const int row  = blockIdx.x;     // 0..4095
  const int lane = threadIdx.x;    // 0..63, two floats each
  if (row < N_) {
    float2 u = ((const float2*)(a  + (size_t)row * DFEAT))[lane];
    float2 w = ((const float2*)(ng + (size_t)row * DFEAT))[lane];
    float saa = u.x * u.x + u.y * u.y;
    float snn = w.x * w.x + w.y * w.y;
    float san = u.x * w.x + u.y * w.y;
#pragma unroll
    for (int m = 1; m < 64; m <<= 1) {
      saa += __shfl_xor(saa, m);
      snn += __shfl_xor(snn, m);
      san += __shfl_xor(san, m);
    }
    float na = fmaxf(sqrtf(saa), 1e-8f);
    float rn = 1.0f / na;
    __hip_bfloat162 h;
    h.x = __float2bfloat16(u.x * rn);
    h.y = __float2bfloat16(u.y * rn);
    ((__hip_bfloat162*)zn16)[row * (DFEAT / 2) + lane] = h;
    if (lane == 0)
      dvec[row] = SCALE * san / (na * fmaxf(sqrtf(snn), 1e-8f));
  } else {
    float2 v = ((const float2*)(p + (size_t)(row - N_) * DFEAT))[lane];
    float ss = v.x * v.x + v.y * v.y;
#pragma unroll
    for (int m = 1; m < 64; m <<= 1) ss += __shfl_xor(ss, m);
    float rn = 1.0f / fmaxf(sqrtf(ss), 1e-8f);
    __hip_bfloat162 h;
    h.x = __float2bfloat16(v.x * rn);
    h.y = __float2bfloat16(v.y * rn);
    ((__hip_bfloat162*)zn16)[row * (DFEAT / 2) + lane] = h;
  }
}

// ---------------------------------------------------------------------------
// Kernel 2: fused G = zn@zn^T /T, exp, masked row-segment partial sums.
//   grid = (TWO_N/64 row strips, CCHUNKS col chunks), block = 256 (4 waves).
//   Each wave owns a 16-row strip; MFMA 16x16x32 bf16 over K=128.
//   C/D layout: col = lane&15, row = (lane>>4)*4 + reg   [m89-verified]
//   Writes accS_part[chunk][row] / accP_part[chunk][row] — NO atomics,
//   every (chunk,row) slot written exactly once (no zero-init needed).
// ---------------------------------------------------------------------------
__global__ __launch_bounds__(256) void k_simsum(const __hip_bfloat16* __restrict__ zn16,
                                                float* __restrict__ accP_part,
                                                float* __restrict__ accS_part) {
  const int wave = threadIdx.x >> 6;
  const int lane = threadIdx.x & 63;
  const int lr   = lane & 15;   // A-row / B-col within tile
  const int kg   = lane >> 4;   // k-group
  const int rows_base = blockIdx.x * 64 + wave * 16;
  const int cb0 = blockIdx.y * CCOLS;
  const short* zs = (const short*)zn16;

  // A fragments for this wave's 16 rows, all K=128 (4 subtiles), kept in regs
  bf16x8 a[4];
#pragma unroll
  for (int kk = 0; kk < 4; ++kk)
    a[kk] = *(const bf16x8*)(zs + (size_t)(rows_base + lr) * DFEAT + kk * 32 + kg * 8);

  const bool hi = (rows_base >= N_);   // strip-uniform (N_ % 64 == 0)
  int rrow[4], prt[4];
#pragma unroll
  for (int j = 0; j < 4; ++j) {
    rrow[j] = rows_base + kg * 4 + j;
    prt[j]  = hi ? (rrow[j] - N_) : (rrow[j] + N_);
  }

  float accPv[4] = {0.f, 0.f, 0.f, 0.f};
  float accSv[4] = {0.f, 0.f, 0.f, 0.f};

  for (int ct = 0; ct < CCOLS / 16; ++ct) {
    const int c = cb0 + ct * 16 + lr;
    bf16x8 b[4];
#pragma unroll
    for (int kk = 0; kk < 4; ++kk)
      b[kk] = *(const bf16x8*)(zs + (size_t)c * DFEAT + kk * 32 + kg * 8);
    f32x4 acc = {0.f, 0.f, 0.f, 0.f};
#pragma unroll
    for (int kk = 0; kk < 4; ++kk)
      acc = __builtin_amdgcn_mfma_f32_16x16x32_bf16(a[kk], b[kk], acc, 0, 0, 0);
#pragma unroll
    for (int j = 0; j < 4; ++j) {
      const int r = rrow[j];
      float e = __expf(SCALE * acc[j]);
      const bool excl = (c == r) || (c == prt[j]);  // diag + masked partner/q
      e = excl ? 0.0f : e;
      if (hi) {
        const bool toP = (c < prt[j]);              // prt = q = r - N
        accPv[j] += toP ? e : 0.0f;
        accSv[j] += toP ? 0.0f : e;
      } else {
        accSv[j] += e;
      }
    }
  }

  // reduce across the 16 lanes sharing this row group, then one write/row
#pragma unroll
  for (int j = 0; j < 4; ++j) {
    float pv = accPv[j], sv = accSv[j];
#pragma unroll
    for (int m = 1; m < 16; m <<= 1) {
      pv += __shfl_xor(pv, m);
      sv += __shfl_xor(sv, m);
    }
    if (lr == 0) {
      accS_part[blockIdx.y * TWO_N + rrow[j]] = sv;
      if (hi) accP_part[blockIdx.y * TWO_N + rrow[j]] = pv;
    }
  }
}

// ---------------------------------------------------------------------------
// Kernel 3: finalize.
//   S[r] = sum_c accS_part[c][r];  P[r] = sum_c accP_part[c][r] (hi rows)
//   row i<N:        log(2*E[i] + S[i]) - d[i]
//   row N+i, i<N-1: log(E[i] + S[N+i] + P[N+i+1]) - d[i]
//   row 2N-1:       log(E[N-1] + S[2N-1] + sum_j E[j]) - d[N-1]
// ---------------------------------------------------------------------------
__global__ __launch_bounds__(1024) void k_final(const float* __restrict__ dvec,
                                                const float* __restrict__ accP_part,
                                                const float* __restrict__ accS_part,
                                                float* __restrict__ out) {
  __shared__ float Elds[N_];
  __shared__ float Plds[N_];   // P[N_ + i] stored at Plds[i]
  __shared__ float red[16];
  const int tid = threadIdx.x;
  float dpart = 0.f;
  for (int i = tid; i < N_; i += 1024) {
    float E = __expf(dvec[i]);
    Elds[i] = E;
    dpart += E;
    float P = 0.f;
#pragma unroll
    for (int c = 0; c < CCHUNKS; ++c) P += accP_part[c * TWO_N + N_ + i];
    Plds[i] = P;
  }
#pragma unroll
  for (int m = 1; m < 64; m <<= 1) dpart += __shfl_xor(dpart, m);
  const int w = tid >> 6, l = tid & 63;
  if (l == 0) red[w] = dpart;
  __syncthreads();
  float Dsum = 0.f;
#pragma unroll
  for (int k = 0; k < 16; ++k) Dsum += red[k];
  __syncthreads();  // before reusing red[]

  float part = 0.f;
  for (int r = tid; r < TWO_N; r += 1024) {
    float S = 0.f;
#pragma unroll
    for (int c = 0; c < CCHUNKS; ++c) S += accS_part[c * TWO_N + r];
    float t;
    if (r < N_) {
      t = logf(2.0f * Elds[r] + S) - dvec[r];
    } else {
      const int i = r - N_;
      const float extra = (i < N_ - 1) ? Plds[i + 1] : Dsum;
      t = logf(Elds[i] + S + extra) - dvec[i];
    }
    part += t;
  }
#pragma unroll
  for (int m = 1; m < 64; m <<= 1) part += __shfl_xor(part, m);
  if (l == 0) red[w] = part;
  __syncthreads();
  if (tid == 0) {
    float tot = 0.f;
#pragma unroll
    for (int k = 0; k < 16; ++k) tot += red[k];
    out[0] = tot / (float)TWO_N;
  }
}

// ---------------------------------------------------------------------------
extern "C" void kernel_launch(void* const* d_in, const int* in_sizes, int n_in,
                              void* d_out, int out_size, void* d_ws, size_t ws_size,
                              hipStream_t stream) {
  const float* a  = (const float*)d_in[0];
  const float* p  = (const float*)d_in[1];
  const float* ng = (const float*)d_in[2];

  char* ws = (char*)d_ws;
  __hip_bfloat16* zn16 = (__hip_bfloat16*)ws;                        // 1 MB
  float* dvec      = (float*)(ws + (size_t)TWO_N * DFEAT * 2);       // 16 KB pad
  float* accP_part = dvec + TWO_N;                                   // 128 KB
  float* accS_part = accP_part + CCHUNKS * TWO_N;                    // 128 KB

  k_prep<<<TWO_N, 64, 0, stream>>>(a, p, ng, zn16, dvec);
  k_simsum<<<dim3(TWO_N / 64, CCHUNKS), 256, 0, stream>>>(zn16, accP_part, accS_part);
  k_final<<<1, 1024, 0, stream>>>(dvec, accP_part, accS_part, (float*)d_out);
}